// Round 1
// baseline (67344.879 us; speedup 1.0000x reference)
//
#include <hip/hip_runtime.h>
#include <hip/hip_bf16.h>

// LeakyRU: y[t] = h_t ;  h_t = z*h_{t-1} + (1-z)*tanh(pre[t] + r*(W_hn @ h_{t-1}))
// pre = x @ W_in^T + bias_n   (W_in = weight_ih[2H:], W_hn = weight_hh[2H:] w/ zero diag)
// T=2048 B=16 I=H=1024.
//
// Phase 1: bf16-MFMA GEMM -> pre (bf16, 67MB in d_ws)
// Phase 2: persistent scan kernel, 256 WGs (16 slices x 16 batches), W_hn slice in
//          fp32 VGPRs, per-batch 16-WG flag sync through agent-scope atomics.

#define T_STEPS 2048
#define NBATCH 16
#define IDIM 1024
#define HDIM 1024

typedef __bf16 bf16x8 __attribute__((ext_vector_type(8)));
typedef float f32x4 __attribute__((ext_vector_type(4)));

__device__ __forceinline__ float fast_sigmoid(float x) {
  return 1.0f / (1.0f + __expf(-x));
}
__device__ __forceinline__ float fast_tanh(float x) {
  // tanh(x) = 1 - 2/(1+e^{2x}); saturates correctly for |x| large.
  float e = __expf(2.0f * x);
  return 1.0f - 2.0f / (e + 1.0f);
}

// ---------------------------------------------------------------------------
// Phase 1: pre[m][n] = sum_k x[m][k] * W_in[n][k] + bias_n[n]   (M=T*B, N=H, K=I)
// 128x128 tile, BK=32, 4 waves (2x2), 16x16x32 bf16 MFMA, reg-staged fp32->bf16.
// ---------------------------------------------------------------------------
__global__ __launch_bounds__(256) void pre_gemm(const float* __restrict__ x,
                                                const float* __restrict__ wih,
                                                const float* __restrict__ bias_n,
                                                __bf16* __restrict__ pre) {
  __shared__ __align__(16) __bf16 As[128][32];
  __shared__ __align__(16) __bf16 Bs[128][32];
  const int tid = threadIdx.x;
  const int lane = tid & 63;
  const int wid = tid >> 6;
  const int wr = wid >> 1;
  const int wc = wid & 1;
  const int nblk = blockIdx.x & 7;   // N/128 = 8
  const int mblk = blockIdx.x >> 3;  // M/128 = 256
  const size_t m0 = (size_t)mblk * 128;
  const int n0 = nblk * 128;
  const float* __restrict__ win = wih + (size_t)2 * HDIM * IDIM;  // W_in rows

  f32x4 acc[4][4] = {};

  const int srow = tid >> 1;         // 0..127
  const int scol = (tid & 1) << 4;   // 0 or 16

  for (int k0 = 0; k0 < IDIM; k0 += 32) {
    const float4* ga = reinterpret_cast<const float4*>(x + (m0 + srow) * IDIM + k0 + scol);
    const float4* gb = reinterpret_cast<const float4*>(win + (size_t)(n0 + srow) * IDIM + k0 + scol);
    float4 a0 = ga[0], a1 = ga[1], a2 = ga[2], a3 = ga[3];
    float4 b0 = gb[0], b1 = gb[1], b2 = gb[2], b3 = gb[3];
    __syncthreads();  // previous iter's ds_reads done before overwrite
    {
      bf16x8 v;
      v[0]=(__bf16)a0.x; v[1]=(__bf16)a0.y; v[2]=(__bf16)a0.z; v[3]=(__bf16)a0.w;
      v[4]=(__bf16)a1.x; v[5]=(__bf16)a1.y; v[6]=(__bf16)a1.z; v[7]=(__bf16)a1.w;
      *reinterpret_cast<bf16x8*>(&As[srow][scol]) = v;
      v[0]=(__bf16)a2.x; v[1]=(__bf16)a2.y; v[2]=(__bf16)a2.z; v[3]=(__bf16)a2.w;
      v[4]=(__bf16)a3.x; v[5]=(__bf16)a3.y; v[6]=(__bf16)a3.z; v[7]=(__bf16)a3.w;
      *reinterpret_cast<bf16x8*>(&As[srow][scol + 8]) = v;
      v[0]=(__bf16)b0.x; v[1]=(__bf16)b0.y; v[2]=(__bf16)b0.z; v[3]=(__bf16)b0.w;
      v[4]=(__bf16)b1.x; v[5]=(__bf16)b1.y; v[6]=(__bf16)b1.z; v[7]=(__bf16)b1.w;
      *reinterpret_cast<bf16x8*>(&Bs[srow][scol]) = v;
      v[0]=(__bf16)b2.x; v[1]=(__bf16)b2.y; v[2]=(__bf16)b2.z; v[3]=(__bf16)b2.w;
      v[4]=(__bf16)b3.x; v[5]=(__bf16)b3.y; v[6]=(__bf16)b3.z; v[7]=(__bf16)b3.w;
      *reinterpret_cast<bf16x8*>(&Bs[srow][scol + 8]) = v;
    }
    __syncthreads();
    const int ko = (lane >> 4) << 3;  // 0,8,16,24
    bf16x8 af[4], bfr[4];
#pragma unroll
    for (int m16 = 0; m16 < 4; ++m16)
      af[m16] = *reinterpret_cast<const bf16x8*>(&As[wr * 64 + m16 * 16 + (lane & 15)][ko]);
#pragma unroll
    for (int n16 = 0; n16 < 4; ++n16)
      bfr[n16] = *reinterpret_cast<const bf16x8*>(&Bs[wc * 64 + n16 * 16 + (lane & 15)][ko]);
#pragma unroll
    for (int m16 = 0; m16 < 4; ++m16)
#pragma unroll
      for (int n16 = 0; n16 < 4; ++n16)
        acc[m16][n16] =
            __builtin_amdgcn_mfma_f32_16x16x32_bf16(af[m16], bfr[n16], acc[m16][n16], 0, 0, 0);
  }

  // epilogue: C[row][col], col = lane&15 (+16*n16), row = (lane>>4)*4+q (+16*m16)
#pragma unroll
  for (int n16 = 0; n16 < 4; ++n16) {
    const int col = n0 + wc * 64 + n16 * 16 + (lane & 15);
    const float bi = bias_n[col];
#pragma unroll
    for (int m16 = 0; m16 < 4; ++m16) {
#pragma unroll
      for (int q = 0; q < 4; ++q) {
        const size_t row = m0 + wr * 64 + m16 * 16 + ((lane >> 4) << 2) + q;
        pre[row * HDIM + col] = (__bf16)(acc[m16][n16][q] + bi);
      }
    }
  }
}

// ---------------------------------------------------------------------------
// Phase 2: persistent scan. grid=256 (1 WG/CU), block=1024 (16 waves).
// WG -> (batch b, slice s): s owns h rows [64s,64s+64). W_hn slice in VGPRs fp32.
// Per wave (wid): 4 rows 4*wid+(lane>>4); lane covers cols (lane&15)*4 + 64c + d.
// Sync: per-batch 16-WG flag protocol, hbuf parity-double-buffered.
// ---------------------------------------------------------------------------
__global__ __launch_bounds__(1024, 4) void leaky_scan(
    const __bf16* __restrict__ pre, const float* __restrict__ whh,
    const float* __restrict__ h0, const float* __restrict__ bias_z,
    const float* __restrict__ bias_r, float* __restrict__ y,
    float* __restrict__ hn, float* hbuf, int* flags) {
  __shared__ __align__(16) float hvec[HDIM];
  __shared__ float dots[64];
  const int tid = threadIdx.x;
  const int lane = tid & 63;
  const int wid = tid >> 6;  // 0..15
  const int g = blockIdx.x;
  // perf-only XCD-affine mapping: batch's 16 WGs co-locate on one XCD (if g%8==XCD)
  const int b = ((g & 7) << 1) | ((g >> 3) & 1);  // 0..15
  const int s = g >> 4;                           // 0..15
  const int base = s << 6;

  // load my 4 W rows (this wave) into registers, zeroing the diagonal
  const int rloc = (wid << 2) + (lane >> 4);  // local row 0..63
  const int R = base + rloc;                  // hidden row index
  const float* wrow = whh + (size_t)(2 * HDIM + R) * HDIM;
  const int cb = (lane & 15) << 2;  // column base 0..60
  f32x4 wreg[16];
#pragma unroll
  for (int c = 0; c < 16; ++c) {
    const int colc = cb + (c << 6);
    f32x4 v = *reinterpret_cast<const f32x4*>(wrow + colc);
    v[0] = (R == colc + 0) ? 0.f : v[0];
    v[1] = (R == colc + 1) ? 0.f : v[1];
    v[2] = (R == colc + 2) ? 0.f : v[2];
    v[3] = (R == colc + 3) ? 0.f : v[3];
    wreg[c] = v;
  }
  hvec[tid] = h0[b * HDIM + tid];
  float zz = 0.f, rr = 0.f, preg = 0.f;
  if (wid == 0) {
    zz = fast_sigmoid(bias_z[base + lane]);
    rr = fast_sigmoid(bias_r[base + lane]);
    preg = (float)pre[(size_t)b * HDIM + base + lane];  // pre[t=0]
  }
  __syncthreads();

  for (int t = 1; t <= T_STEPS; ++t) {
    // --- matvec: dot[row] = sum_j W[row][j] * h[j]
    float acc = 0.f;
#pragma unroll
    for (int c = 0; c < 16; ++c) {
      f32x4 hv = *reinterpret_cast<const f32x4*>(&hvec[cb + (c << 6)]);
      acc += wreg[c][0] * hv[0];
      acc += wreg[c][1] * hv[1];
      acc += wreg[c][2] * hv[2];
      acc += wreg[c][3] * hv[3];
    }
    acc += __shfl_xor(acc, 1);
    acc += __shfl_xor(acc, 2);
    acc += __shfl_xor(acc, 4);
    acc += __shfl_xor(acc, 8);
    if ((lane & 15) == 0) dots[rloc] = acc;
    __syncthreads();  // dots ready

    if (wid == 0) {
      // pointwise + publish (lane i <-> hidden row base+i)
      const float dot = dots[lane];
      const float hp = hvec[base + lane];
      const float nn = fast_tanh(preg + rr * dot);
      const float hnew = zz * hp + (1.0f - zz) * nn;
      if (t < T_STEPS) {
        __hip_atomic_store(&hbuf[(size_t)((t & 1) * NBATCH + b) * HDIM + base + lane], hnew,
                           __ATOMIC_RELAXED, __HIP_MEMORY_SCOPE_AGENT);
        if (lane == 0)
          __hip_atomic_store(&flags[b * 16 + s], t, __ATOMIC_RELEASE, __HIP_MEMORY_SCOPE_AGENT);
      }
      __builtin_amdgcn_sched_barrier(0);  // keep y/pre traffic out of the release waitcnt
      y[((size_t)(t - 1) * NBATCH + b) * HDIM + base + lane] = hnew;
      if (t == T_STEPS) hn[b * HDIM + base + lane] = hnew;
      hvec[base + lane] = hnew;  // own slice locally (excluded from gather)
      if (t < T_STEPS)  // prefetch pre for step t+1 (hidden under next matvec)
        preg = (float)pre[((size_t)t * NBATCH + b) * HDIM + base + lane];
    } else if (wid == 1) {
      if (t < T_STEPS && lane < 16 && lane != s) {
        while (__hip_atomic_load(&flags[b * 16 + lane], __ATOMIC_RELAXED,
                                 __HIP_MEMORY_SCOPE_AGENT) < t) {
        }
      }
    }
    __syncthreads();  // flags observed + own slice in LDS

    if (t < T_STEPS) {
      __builtin_amdgcn_fence(__ATOMIC_ACQUIRE, "agent");
      if (wid != s) {
        hvec[tid] = __hip_atomic_load(&hbuf[(size_t)((t & 1) * NBATCH + b) * HDIM + tid],
                                      __ATOMIC_RELAXED, __HIP_MEMORY_SCOPE_AGENT);
      }
      __syncthreads();  // hvec = h_t complete
    }
  }
}

// ---------------------------------------------------------------------------
extern "C" void kernel_launch(void* const* d_in, const int* in_sizes, int n_in,
                              void* d_out, int out_size, void* d_ws, size_t ws_size,
                              hipStream_t stream) {
  const float* x = (const float*)d_in[0];
  const float* h0 = (const float*)d_in[1];
  const float* wih = (const float*)d_in[2];
  const float* whh = (const float*)d_in[3];
  const float* bz = (const float*)d_in[4];
  const float* bn = (const float*)d_in[5];
  const float* br = (const float*)d_in[6];
  float* y = (float*)d_out;
  float* hn = y + (size_t)T_STEPS * NBATCH * HDIM;

  // workspace layout: pre (bf16, 67MB) | hbuf (2*16*1024 f32) | flags (16*16 int)
  __bf16* pre = (__bf16*)d_ws;
  float* hbuf = (float*)((char*)d_ws + (size_t)T_STEPS * NBATCH * HDIM * sizeof(__bf16));
  int* flags = (int*)((char*)hbuf + (size_t)2 * NBATCH * HDIM * sizeof(float));

  hipMemsetAsync(flags, 0, NBATCH * 16 * sizeof(int), stream);
  pre_gemm<<<dim3(2048), dim3(256), 0, stream>>>(x, wih, bn, pre);
  leaky_scan<<<dim3(256), dim3(1024), 0, stream>>>(pre, whh, h0, bz, br, y, hn, hbuf, flags);
}

// Round 4
// 19633.105 us; speedup vs baseline: 3.4302x; 3.4302x over previous
//
#include <hip/hip_runtime.h>
#include <hip/hip_bf16.h>

// LeakyRU: y[t] = h_t ;  h_t = z*h_{t-1} + (1-z)*tanh(pre[t] + r*(W_hn @ h_{t-1}))
// pre = x @ W_in^T + bias_n   (W_in = weight_ih[2H:], W_hn = weight_hh[2H:] w/ zero diag)
// T=2048 B=16 I=H=1024.
//
// Phase 1: bf16-MFMA GEMM -> pre (bf16, 67MB in d_ws)
// Phase 2: persistent scan, 256 WGs (16 slices x 16 batches), W slice in fp32 regs.
//   Fence-free cross-XCD exchange: h published into y via atomic swap (RMW executes
//   at the LLC coherence point), per-batch arrival counter via atomic add, consumers
//   spin with RMW(+0) + s_sleep, gather h_{t} from y with plain loads (virgin
//   addresses each step -> no stale L2 line can exist; kernel-start invalidate
//   covers pre-launch poison). NO agent release/acquire fences in the loop --
//   round-1's buffer_wbl2/buffer_inv per WG per step was the 33us/step stall.

#define T_STEPS 2048
#define NBATCH 16
#define IDIM 1024
#define HDIM 1024

typedef __bf16 bf16x8 __attribute__((ext_vector_type(8)));
typedef float f32x4 __attribute__((ext_vector_type(4)));

__device__ __forceinline__ float fast_sigmoid(float x) {
  return 1.0f / (1.0f + __expf(-x));
}
__device__ __forceinline__ float fast_tanh(float x) {
  float e = __expf(2.0f * x);
  return 1.0f - 2.0f / (e + 1.0f);
}

// ---------------------------------------------------------------------------
// Phase 1: pre[m][n] = sum_k x[m][k] * W_in[n][k] + bias_n[n]   (M=T*B, N=H, K=I)
// (unchanged from round 1 -- verified correct, <0.5ms)
// ---------------------------------------------------------------------------
__global__ __launch_bounds__(256) void pre_gemm(const float* __restrict__ x,
                                                const float* __restrict__ wih,
                                                const float* __restrict__ bias_n,
                                                __bf16* __restrict__ pre) {
  __shared__ __align__(16) __bf16 As[128][32];
  __shared__ __align__(16) __bf16 Bs[128][32];
  const int tid = threadIdx.x;
  const int lane = tid & 63;
  const int wid = tid >> 6;
  const int wr = wid >> 1;
  const int wc = wid & 1;
  const int nblk = blockIdx.x & 7;
  const int mblk = blockIdx.x >> 3;
  const size_t m0 = (size_t)mblk * 128;
  const int n0 = nblk * 128;
  const float* __restrict__ win = wih + (size_t)2 * HDIM * IDIM;

  f32x4 acc[4][4] = {};

  const int srow = tid >> 1;
  const int scol = (tid & 1) << 4;

  for (int k0 = 0; k0 < IDIM; k0 += 32) {
    const float4* ga = reinterpret_cast<const float4*>(x + (m0 + srow) * IDIM + k0 + scol);
    const float4* gb = reinterpret_cast<const float4*>(win + (size_t)(n0 + srow) * IDIM + k0 + scol);
    float4 a0 = ga[0], a1 = ga[1], a2 = ga[2], a3 = ga[3];
    float4 b0 = gb[0], b1 = gb[1], b2 = gb[2], b3 = gb[3];
    __syncthreads();
    {
      bf16x8 v;
      v[0]=(__bf16)a0.x; v[1]=(__bf16)a0.y; v[2]=(__bf16)a0.z; v[3]=(__bf16)a0.w;
      v[4]=(__bf16)a1.x; v[5]=(__bf16)a1.y; v[6]=(__bf16)a1.z; v[7]=(__bf16)a1.w;
      *reinterpret_cast<bf16x8*>(&As[srow][scol]) = v;
      v[0]=(__bf16)a2.x; v[1]=(__bf16)a2.y; v[2]=(__bf16)a2.z; v[3]=(__bf16)a2.w;
      v[4]=(__bf16)a3.x; v[5]=(__bf16)a3.y; v[6]=(__bf16)a3.z; v[7]=(__bf16)a3.w;
      *reinterpret_cast<bf16x8*>(&As[srow][scol + 8]) = v;
      v[0]=(__bf16)b0.x; v[1]=(__bf16)b0.y; v[2]=(__bf16)b0.z; v[3]=(__bf16)b0.w;
      v[4]=(__bf16)b1.x; v[5]=(__bf16)b1.y; v[6]=(__bf16)b1.z; v[7]=(__bf16)b1.w;
      *reinterpret_cast<bf16x8*>(&Bs[srow][scol]) = v;
      v[0]=(__bf16)b2.x; v[1]=(__bf16)b2.y; v[2]=(__bf16)b2.z; v[3]=(__bf16)b2.w;
      v[4]=(__bf16)b3.x; v[5]=(__bf16)b3.y; v[6]=(__bf16)b3.z; v[7]=(__bf16)b3.w;
      *reinterpret_cast<bf16x8*>(&Bs[srow][scol + 8]) = v;
    }
    __syncthreads();
    const int ko = (lane >> 4) << 3;
    bf16x8 af[4], bfr[4];
#pragma unroll
    for (int m16 = 0; m16 < 4; ++m16)
      af[m16] = *reinterpret_cast<const bf16x8*>(&As[wr * 64 + m16 * 16 + (lane & 15)][ko]);
#pragma unroll
    for (int n16 = 0; n16 < 4; ++n16)
      bfr[n16] = *reinterpret_cast<const bf16x8*>(&Bs[wc * 64 + n16 * 16 + (lane & 15)][ko]);
#pragma unroll
    for (int m16 = 0; m16 < 4; ++m16)
#pragma unroll
      for (int n16 = 0; n16 < 4; ++n16)
        acc[m16][n16] =
            __builtin_amdgcn_mfma_f32_16x16x32_bf16(af[m16], bfr[n16], acc[m16][n16], 0, 0, 0);
  }

#pragma unroll
  for (int n16 = 0; n16 < 4; ++n16) {
    const int col = n0 + wc * 64 + n16 * 16 + (lane & 15);
    const float bi = bias_n[col];
#pragma unroll
    for (int m16 = 0; m16 < 4; ++m16) {
#pragma unroll
      for (int q = 0; q < 4; ++q) {
        const size_t row = m0 + wr * 64 + m16 * 16 + ((lane >> 4) << 2) + q;
        pre[row * HDIM + col] = (__bf16)(acc[m16][n16][q] + bi);
      }
    }
  }
}

// ---------------------------------------------------------------------------
// Phase 2: persistent scan. grid=256, block=1024 (16 waves). WG -> (b, s):
// slice s owns h rows [64s, 64s+64). Fence-free LLC-mediated exchange (see top).
// ---------------------------------------------------------------------------
__global__ __launch_bounds__(1024) void leaky_scan(
    const __bf16* __restrict__ pre, const float* __restrict__ whh,
    const float* __restrict__ h0, const float* __restrict__ bias_z,
    const float* __restrict__ bias_r, float* __restrict__ y,
    float* __restrict__ hn, int* cnt) {
  __shared__ __align__(16) float hvec[HDIM];
  __shared__ float dots[64];
  const int tid = threadIdx.x;
  const int lane = tid & 63;
  const int wid = tid >> 6;  // 0..15
  const int g = blockIdx.x;
  const int b = g & 15;   // batch
  const int s = g >> 4;   // slice
  const int base = s << 6;

  // my 4 W rows (fp32) in registers, diagonal zeroed
  const int rloc = (wid << 2) + (lane >> 4);  // local row 0..63
  const int R = base + rloc;
  const float* wrow = whh + (size_t)(2 * HDIM + R) * HDIM;
  const int cb = (lane & 15) << 2;
  f32x4 wreg[16];
#pragma unroll
  for (int c = 0; c < 16; ++c) {
    const int colc = cb + (c << 6);
    f32x4 v = *reinterpret_cast<const f32x4*>(wrow + colc);
    v[0] = (R == colc + 0) ? 0.f : v[0];
    v[1] = (R == colc + 1) ? 0.f : v[1];
    v[2] = (R == colc + 2) ? 0.f : v[2];
    v[3] = (R == colc + 3) ? 0.f : v[3];
    wreg[c] = v;
  }
  hvec[tid] = h0[b * HDIM + tid];
  float zz = 0.f, rr = 0.f, preg = 0.f;
  if (wid == 0) {
    zz = fast_sigmoid(bias_z[base + lane]);
    rr = fast_sigmoid(bias_r[base + lane]);
    preg = (float)pre[(size_t)b * HDIM + base + lane];  // pre[t=0]
  }
  int* const cb_ptr = &cnt[b];
  __syncthreads();

  for (int t = 1; t <= T_STEPS; ++t) {
    // matvec: dot[row] = sum_j W[row][j] * h[j]  (4 split accumulators)
    float a0 = 0.f, a1 = 0.f, a2 = 0.f, a3 = 0.f;
#pragma unroll
    for (int c = 0; c < 4; ++c) {
      f32x4 h0v = *reinterpret_cast<const f32x4*>(&hvec[cb + ((4 * c + 0) << 6)]);
      f32x4 h1v = *reinterpret_cast<const f32x4*>(&hvec[cb + ((4 * c + 1) << 6)]);
      f32x4 h2v = *reinterpret_cast<const f32x4*>(&hvec[cb + ((4 * c + 2) << 6)]);
      f32x4 h3v = *reinterpret_cast<const f32x4*>(&hvec[cb + ((4 * c + 3) << 6)]);
      const f32x4 w0 = wreg[4 * c + 0], w1 = wreg[4 * c + 1];
      const f32x4 w2 = wreg[4 * c + 2], w3 = wreg[4 * c + 3];
      a0 += w0[0]*h0v[0] + w0[1]*h0v[1] + w0[2]*h0v[2] + w0[3]*h0v[3];
      a1 += w1[0]*h1v[0] + w1[1]*h1v[1] + w1[2]*h1v[2] + w1[3]*h1v[3];
      a2 += w2[0]*h2v[0] + w2[1]*h2v[1] + w2[2]*h2v[2] + w2[3]*h2v[3];
      a3 += w3[0]*h3v[0] + w3[1]*h3v[1] + w3[2]*h3v[2] + w3[3]*h3v[3];
    }
    float acc = (a0 + a1) + (a2 + a3);
    acc += __shfl_xor(acc, 1);
    acc += __shfl_xor(acc, 2);
    acc += __shfl_xor(acc, 4);
    acc += __shfl_xor(acc, 8);
    if ((lane & 15) == 0) dots[rloc] = acc;
    __syncthreads();  // dots ready

    if (wid == 0) {
      const float dot = dots[lane];
      const float hp = hvec[base + lane];
      const float nn = fast_tanh(preg + rr * dot);
      const float hnew = zz * hp + (1.0f - zz) * nn;
      // publish h_t into y[t-1] via RMW swap (executes at LLC -> cross-XCD visible)
      (void)__hip_atomic_exchange(&y[((size_t)(t - 1) * NBATCH + b) * HDIM + base + lane],
                                  hnew, __ATOMIC_RELAXED, __HIP_MEMORY_SCOPE_AGENT);
      if (t < T_STEPS) {
        asm volatile("s_waitcnt vmcnt(0)" ::: "memory");  // swap committed at LLC
        if (lane == 0)
          (void)__hip_atomic_fetch_add(cb_ptr, 1, __ATOMIC_RELAXED, __HIP_MEMORY_SCOPE_AGENT);
        // prefetch pre[t] for step t+1 (off the critical path, hides under spin/gather)
        preg = (float)pre[((size_t)t * NBATCH + b) * HDIM + base + lane];
      } else {
        hn[b * HDIM + base + lane] = hnew;
      }
    } else if (wid == 1 && lane == 0 && t < T_STEPS) {
      const int target = t * 16;  // all 16 slices of batch b published step t
      while (__hip_atomic_fetch_add(cb_ptr, 0, __ATOMIC_RELAXED, __HIP_MEMORY_SCOPE_AGENT) <
             target) {
        __builtin_amdgcn_s_sleep(1);
      }
    }
    __syncthreads();  // counter observed

    if (t < T_STEPS) {
      asm volatile("" ::: "memory");
      // gather h_t from y[t-1] (plain loads; virgin addresses -> always fresh via LLC)
      hvec[tid] = y[((size_t)(t - 1) * NBATCH + b) * HDIM + tid];
      __syncthreads();  // hvec = h_t complete
    }
  }
}

// ---------------------------------------------------------------------------
extern "C" void kernel_launch(void* const* d_in, const int* in_sizes, int n_in,
                              void* d_out, int out_size, void* d_ws, size_t ws_size,
                              hipStream_t stream) {
  const float* x = (const float*)d_in[0];
  const float* h0 = (const float*)d_in[1];
  const float* wih = (const float*)d_in[2];
  const float* whh = (const float*)d_in[3];
  const float* bz = (const float*)d_in[4];
  const float* bn = (const float*)d_in[5];
  const float* br = (const float*)d_in[6];
  float* y = (float*)d_out;
  float* hn = y + (size_t)T_STEPS * NBATCH * HDIM;

  // workspace: pre (bf16, 67MB) | cnt (16 ints)
  __bf16* pre = (__bf16*)d_ws;
  int* cnt = (int*)((char*)d_ws + (size_t)T_STEPS * NBATCH * HDIM * sizeof(__bf16));

  hipMemsetAsync(cnt, 0, NBATCH * sizeof(int), stream);
  pre_gemm<<<dim3(2048), dim3(256), 0, stream>>>(x, wih, bn, pre);
  leaky_scan<<<dim3(256), dim3(1024), 0, stream>>>(pre, whh, h0, bz, br, y, hn, cnt);
}

// Round 5
// 4665.173 us; speedup vs baseline: 14.4357x; 4.2084x over previous
//
#include <hip/hip_runtime.h>
#include <hip/hip_bf16.h>

// LeakyRU: y[t] = h_t ;  h_t = z*h_{t-1} + (1-z)*tanh(pre[t] + r*(W_hn @ h_{t-1}))
// pre = x @ W_in^T + bias_n   (W_in = weight_ih[2H:], W_hn = weight_hh[2H:] w/ zero diag)
// T=2048 B=16 I=H=1024.
//
// Phase 1: bf16-MFMA GEMM -> pre (bf16, 67MB in d_ws)
// Phase 2: persistent scan, 256 WGs (16 slices x 16 batches), W slice in fp32 regs.
//   Round-4 postmortem: counter RMW contention + producer's two dependent LLC round
//   trips dominated (9.2us/step). Now: data-is-the-flag. Each h value published as
//   u64 (tag<<32 | bits) via relaxed agent atomic_exchange (non-returning) into a
//   parity double buffer; consumers poll the words directly with relaxed agent
//   atomic LOADS (L2-bypassing, contention-free) until tag==t. No vmcnt drain, no
//   flags, no counter. Depth-2 parity is sufficient: publish(t+2) transitively
//   requires our gather(t) complete. Tag equality defeats ABA + 0xAA poison.

#define T_STEPS 2048
#define NBATCH 16
#define IDIM 1024
#define HDIM 1024

typedef __bf16 bf16x8 __attribute__((ext_vector_type(8)));
typedef float f32x4 __attribute__((ext_vector_type(4)));

__device__ __forceinline__ float fast_sigmoid(float x) {
  return 1.0f / (1.0f + __expf(-x));
}
__device__ __forceinline__ float fast_tanh(float x) {
  float e = __expf(2.0f * x);
  return 1.0f - 2.0f / (e + 1.0f);
}

// ---------------------------------------------------------------------------
// Phase 1: pre[m][n] = sum_k x[m][k] * W_in[n][k] + bias_n[n]   (M=T*B, N=H, K=I)
// (unchanged -- verified correct, ~0.3ms)
// ---------------------------------------------------------------------------
__global__ __launch_bounds__(256) void pre_gemm(const float* __restrict__ x,
                                                const float* __restrict__ wih,
                                                const float* __restrict__ bias_n,
                                                __bf16* __restrict__ pre) {
  __shared__ __align__(16) __bf16 As[128][32];
  __shared__ __align__(16) __bf16 Bs[128][32];
  const int tid = threadIdx.x;
  const int lane = tid & 63;
  const int wid = tid >> 6;
  const int wr = wid >> 1;
  const int wc = wid & 1;
  const int nblk = blockIdx.x & 7;
  const int mblk = blockIdx.x >> 3;
  const size_t m0 = (size_t)mblk * 128;
  const int n0 = nblk * 128;
  const float* __restrict__ win = wih + (size_t)2 * HDIM * IDIM;

  f32x4 acc[4][4] = {};

  const int srow = tid >> 1;
  const int scol = (tid & 1) << 4;

  for (int k0 = 0; k0 < IDIM; k0 += 32) {
    const float4* ga = reinterpret_cast<const float4*>(x + (m0 + srow) * IDIM + k0 + scol);
    const float4* gb = reinterpret_cast<const float4*>(win + (size_t)(n0 + srow) * IDIM + k0 + scol);
    float4 a0 = ga[0], a1 = ga[1], a2 = ga[2], a3 = ga[3];
    float4 b0 = gb[0], b1 = gb[1], b2 = gb[2], b3 = gb[3];
    __syncthreads();
    {
      bf16x8 v;
      v[0]=(__bf16)a0.x; v[1]=(__bf16)a0.y; v[2]=(__bf16)a0.z; v[3]=(__bf16)a0.w;
      v[4]=(__bf16)a1.x; v[5]=(__bf16)a1.y; v[6]=(__bf16)a1.z; v[7]=(__bf16)a1.w;
      *reinterpret_cast<bf16x8*>(&As[srow][scol]) = v;
      v[0]=(__bf16)a2.x; v[1]=(__bf16)a2.y; v[2]=(__bf16)a2.z; v[3]=(__bf16)a2.w;
      v[4]=(__bf16)a3.x; v[5]=(__bf16)a3.y; v[6]=(__bf16)a3.z; v[7]=(__bf16)a3.w;
      *reinterpret_cast<bf16x8*>(&As[srow][scol + 8]) = v;
      v[0]=(__bf16)b0.x; v[1]=(__bf16)b0.y; v[2]=(__bf16)b0.z; v[3]=(__bf16)b0.w;
      v[4]=(__bf16)b1.x; v[5]=(__bf16)b1.y; v[6]=(__bf16)b1.z; v[7]=(__bf16)b1.w;
      *reinterpret_cast<bf16x8*>(&Bs[srow][scol]) = v;
      v[0]=(__bf16)b2.x; v[1]=(__bf16)b2.y; v[2]=(__bf16)b2.z; v[3]=(__bf16)b2.w;
      v[4]=(__bf16)b3.x; v[5]=(__bf16)b3.y; v[6]=(__bf16)b3.z; v[7]=(__bf16)b3.w;
      *reinterpret_cast<bf16x8*>(&Bs[srow][scol + 8]) = v;
    }
    __syncthreads();
    const int ko = (lane >> 4) << 3;
    bf16x8 af[4], bfr[4];
#pragma unroll
    for (int m16 = 0; m16 < 4; ++m16)
      af[m16] = *reinterpret_cast<const bf16x8*>(&As[wr * 64 + m16 * 16 + (lane & 15)][ko]);
#pragma unroll
    for (int n16 = 0; n16 < 4; ++n16)
      bfr[n16] = *reinterpret_cast<const bf16x8*>(&Bs[wc * 64 + n16 * 16 + (lane & 15)][ko]);
#pragma unroll
    for (int m16 = 0; m16 < 4; ++m16)
#pragma unroll
      for (int n16 = 0; n16 < 4; ++n16)
        acc[m16][n16] =
            __builtin_amdgcn_mfma_f32_16x16x32_bf16(af[m16], bfr[n16], acc[m16][n16], 0, 0, 0);
  }

#pragma unroll
  for (int n16 = 0; n16 < 4; ++n16) {
    const int col = n0 + wc * 64 + n16 * 16 + (lane & 15);
    const float bi = bias_n[col];
#pragma unroll
    for (int m16 = 0; m16 < 4; ++m16) {
#pragma unroll
      for (int q = 0; q < 4; ++q) {
        const size_t row = m0 + wr * 64 + m16 * 16 + ((lane >> 4) << 2) + q;
        pre[row * HDIM + col] = (__bf16)(acc[m16][n16][q] + bi);
      }
    }
  }
}

// ---------------------------------------------------------------------------
// Phase 2: persistent scan. grid=256, block=1024 (16 waves). WG -> (b, s):
// slice s owns h rows [64s, 64s+64). Data-is-the-flag exchange (see header).
// Wave 0: pointwise + publish own slice. Waves 1..15: poll+gather one remote
// slice each ((s+wid)&15). 2 barriers/step.
// ---------------------------------------------------------------------------
__global__ __launch_bounds__(1024) void leaky_scan(
    const __bf16* __restrict__ pre, const float* __restrict__ whh,
    const float* __restrict__ h0, const float* __restrict__ bias_z,
    const float* __restrict__ bias_r, float* __restrict__ y,
    float* __restrict__ hn, unsigned long long* hbuf) {
  __shared__ __align__(16) float hvec[HDIM];
  __shared__ float dots[64];
  const int tid = threadIdx.x;
  const int lane = tid & 63;
  const int wid = tid >> 6;  // 0..15
  const int g = blockIdx.x;
  const int b = g & 15;   // batch
  const int s = g >> 4;   // slice
  const int base = s << 6;

  // my 4 W rows (fp32) in registers, diagonal zeroed
  const int rloc = (wid << 2) + (lane >> 4);  // local row 0..63
  const int R = base + rloc;
  const float* wrow = whh + (size_t)(2 * HDIM + R) * HDIM;
  const int cb = (lane & 15) << 2;
  f32x4 wreg[16];
#pragma unroll
  for (int c = 0; c < 16; ++c) {
    const int colc = cb + (c << 6);
    f32x4 v = *reinterpret_cast<const f32x4*>(wrow + colc);
    v[0] = (R == colc + 0) ? 0.f : v[0];
    v[1] = (R == colc + 1) ? 0.f : v[1];
    v[2] = (R == colc + 2) ? 0.f : v[2];
    v[3] = (R == colc + 3) ? 0.f : v[3];
    wreg[c] = v;
  }
  hvec[tid] = h0[b * HDIM + tid];
  float zz = 0.f, rr = 0.f, preg = 0.f;
  if (wid == 0) {
    zz = fast_sigmoid(bias_z[base + lane]);
    rr = fast_sigmoid(bias_r[base + lane]);
    preg = (float)pre[(size_t)b * HDIM + base + lane];  // pre[t=0]
  }
  // remote-slice gather target for this wave (waves 1..15)
  const int sg = (s + wid) & 15;
  const int jg = (sg << 6) + lane;
  __syncthreads();

  for (int t = 1; t <= T_STEPS; ++t) {
    // matvec: dot[row] = sum_j W[row][j] * h[j]  (4 split accumulators)
    float a0 = 0.f, a1 = 0.f, a2 = 0.f, a3 = 0.f;
#pragma unroll
    for (int c = 0; c < 4; ++c) {
      f32x4 h0v = *reinterpret_cast<const f32x4*>(&hvec[cb + ((4 * c + 0) << 6)]);
      f32x4 h1v = *reinterpret_cast<const f32x4*>(&hvec[cb + ((4 * c + 1) << 6)]);
      f32x4 h2v = *reinterpret_cast<const f32x4*>(&hvec[cb + ((4 * c + 2) << 6)]);
      f32x4 h3v = *reinterpret_cast<const f32x4*>(&hvec[cb + ((4 * c + 3) << 6)]);
      const f32x4 w0 = wreg[4 * c + 0], w1 = wreg[4 * c + 1];
      const f32x4 w2 = wreg[4 * c + 2], w3 = wreg[4 * c + 3];
      a0 += w0[0]*h0v[0] + w0[1]*h0v[1] + w0[2]*h0v[2] + w0[3]*h0v[3];
      a1 += w1[0]*h1v[0] + w1[1]*h1v[1] + w1[2]*h1v[2] + w1[3]*h1v[3];
      a2 += w2[0]*h2v[0] + w2[1]*h2v[1] + w2[2]*h2v[2] + w2[3]*h2v[3];
      a3 += w3[0]*h3v[0] + w3[1]*h3v[1] + w3[2]*h3v[2] + w3[3]*h3v[3];
    }
    float acc = (a0 + a1) + (a2 + a3);
    acc += __shfl_xor(acc, 1);
    acc += __shfl_xor(acc, 2);
    acc += __shfl_xor(acc, 4);
    acc += __shfl_xor(acc, 8);
    if ((lane & 15) == 0) dots[rloc] = acc;
    __syncthreads();  // dots ready; also: all matvec reads of hvec done

    const size_t slot = ((size_t)(t & 1) * NBATCH + b) << 10;  // parity buffer base

    if (wid == 0) {
      __builtin_amdgcn_s_setprio(1);
      const float dot = dots[lane];
      const float hp = hvec[base + lane];
      const float nn = fast_tanh(preg + rr * dot);
      const float hnew = zz * hp + (1.0f - zz) * nn;
      if (t < T_STEPS) {
        // publish (tag<<32 | bits) -- fire-and-forget RMW swap, commits at LLC
        const unsigned long long pv =
            (unsigned long long)__float_as_uint(hnew) | ((unsigned long long)(unsigned)t << 32);
        (void)__hip_atomic_exchange(&hbuf[slot + base + lane], pv, __ATOMIC_RELAXED,
                                    __HIP_MEMORY_SCOPE_AGENT);
      }
      __builtin_amdgcn_s_setprio(0);
      hvec[base + lane] = hnew;  // own slice locally
      y[((size_t)(t - 1) * NBATCH + b) * HDIM + base + lane] = hnew;
      if (t < T_STEPS)
        preg = (float)pre[((size_t)t * NBATCH + b) * HDIM + base + lane];  // prefetch t+1
      else
        hn[b * HDIM + base + lane] = hnew;
    } else if (t < T_STEPS) {
      // poll my remote word until its embedded tag == t, then land it in LDS
      unsigned long long v;
      do {
        v = __hip_atomic_load(&hbuf[slot + jg], __ATOMIC_RELAXED, __HIP_MEMORY_SCOPE_AGENT);
      } while ((unsigned)(v >> 32) != (unsigned)t);
      hvec[jg] = __uint_as_float((unsigned)v);
    }
    __syncthreads();  // hvec = h_t complete
  }
}

// ---------------------------------------------------------------------------
extern "C" void kernel_launch(void* const* d_in, const int* in_sizes, int n_in,
                              void* d_out, int out_size, void* d_ws, size_t ws_size,
                              hipStream_t stream) {
  const float* x = (const float*)d_in[0];
  const float* h0 = (const float*)d_in[1];
  const float* wih = (const float*)d_in[2];
  const float* whh = (const float*)d_in[3];
  const float* bz = (const float*)d_in[4];
  const float* bn = (const float*)d_in[5];
  const float* br = (const float*)d_in[6];
  float* y = (float*)d_out;
  float* hn = y + (size_t)T_STEPS * NBATCH * HDIM;

  // workspace: pre (bf16, 67MB) | hbuf (u64[2][16][1024], 256KB)
  __bf16* pre = (__bf16*)d_ws;
  unsigned long long* hbuf =
      (unsigned long long*)((char*)d_ws + (size_t)T_STEPS * NBATCH * HDIM * sizeof(__bf16));

  // no memset needed: tag-equality polling treats 0xAA poison as "not ready"
  pre_gemm<<<dim3(2048), dim3(256), 0, stream>>>(x, wih, bn, pre);
  leaky_scan<<<dim3(256), dim3(1024), 0, stream>>>(pre, whh, h0, bz, br, y, hn, hbuf);
}

// Round 7
// 3367.260 us; speedup vs baseline: 19.9999x; 1.3855x over previous
//
#include <hip/hip_runtime.h>
#include <hip/hip_bf16.h>

// LeakyRU: y[t] = h_t ;  h_t = z*h_{t-1} + (1-z)*tanh(pre[t] + r*(W_hn @ h_{t-1}))
// pre = x @ W_in^T + bias_n   (W_in = weight_ih[2H:], W_hn = weight_hh[2H:] w/ zero diag)
// T=2048 B=16 I=H=1024.
//
// Phase 1: bf16-MFMA GEMM -> pre (bf16, 67MB in d_ws)
// Phase 2: persistent scan, 256 WGs (16 slices x 16 batches), W slice in fp32 regs.
//   Round-5 postmortem: 2.14us/step = ~1.1us LLC exchange (irreducible 2 one-way
//   trips) + ~0.7us structure (dots barrier + wave-0 pointwise funnel + 2nd barrier
//   + poll storm). Now: DISTRIBUTED pointwise -- each wave's lead lanes finish and
//   publish their own 4 rows right after their shfl-reduce (no dots array, no dots
//   barrier, publishes start ~0.3us earlier); hvec parity-double-buffered in LDS so
//   ONE barrier/step suffices; poll loop throttled with s_sleep(1).
//   Exchange protocol unchanged from round 5 (proven): u64 (tag<<32|bits) published
//   via relaxed agent atomic_exchange into parity slots; consumers poll with relaxed
//   agent atomic loads until tag==t. Depth-2 parity safe (publish(t+2) transitively
//   requires remote gather(t) complete); tag equality defeats ABA + 0xAA poison.

#define T_STEPS 2048
#define NBATCH 16
#define IDIM 1024
#define HDIM 1024

typedef __bf16 bf16x8 __attribute__((ext_vector_type(8)));
typedef float f32x4 __attribute__((ext_vector_type(4)));

__device__ __forceinline__ float fast_sigmoid(float x) {
  return 1.0f / (1.0f + __expf(-x));
}
__device__ __forceinline__ float fast_tanh(float x) {
  float e = __expf(2.0f * x);
  return 1.0f - 2.0f / (e + 1.0f);
}

// ---------------------------------------------------------------------------
// Phase 1: pre[m][n] = sum_k x[m][k] * W_in[n][k] + bias_n[n]   (M=T*B, N=H, K=I)
// (unchanged -- verified correct, ~0.3ms)
// ---------------------------------------------------------------------------
__global__ __launch_bounds__(256) void pre_gemm(const float* __restrict__ x,
                                                const float* __restrict__ wih,
                                                const float* __restrict__ bias_n,
                                                __bf16* __restrict__ pre) {
  __shared__ __align__(16) __bf16 As[128][32];
  __shared__ __align__(16) __bf16 Bs[128][32];
  const int tid = threadIdx.x;
  const int lane = tid & 63;
  const int wid = tid >> 6;
  const int wr = wid >> 1;
  const int wc = wid & 1;
  const int nblk = blockIdx.x & 7;
  const int mblk = blockIdx.x >> 3;
  const size_t m0 = (size_t)mblk * 128;
  const int n0 = nblk * 128;
  const float* __restrict__ win = wih + (size_t)2 * HDIM * IDIM;

  f32x4 acc[4][4] = {};

  const int srow = tid >> 1;
  const int scol = (tid & 1) << 4;

  for (int k0 = 0; k0 < IDIM; k0 += 32) {
    const float4* ga = reinterpret_cast<const float4*>(x + (m0 + srow) * IDIM + k0 + scol);
    const float4* gb = reinterpret_cast<const float4*>(win + (size_t)(n0 + srow) * IDIM + k0 + scol);
    float4 a0 = ga[0], a1 = ga[1], a2 = ga[2], a3 = ga[3];
    float4 b0 = gb[0], b1 = gb[1], b2 = gb[2], b3 = gb[3];
    __syncthreads();
    {
      bf16x8 v;
      v[0]=(__bf16)a0.x; v[1]=(__bf16)a0.y; v[2]=(__bf16)a0.z; v[3]=(__bf16)a0.w;
      v[4]=(__bf16)a1.x; v[5]=(__bf16)a1.y; v[6]=(__bf16)a1.z; v[7]=(__bf16)a1.w;
      *reinterpret_cast<bf16x8*>(&As[srow][scol]) = v;
      v[0]=(__bf16)a2.x; v[1]=(__bf16)a2.y; v[2]=(__bf16)a2.z; v[3]=(__bf16)a2.w;
      v[4]=(__bf16)a3.x; v[5]=(__bf16)a3.y; v[6]=(__bf16)a3.z; v[7]=(__bf16)a3.w;
      *reinterpret_cast<bf16x8*>(&As[srow][scol + 8]) = v;
      v[0]=(__bf16)b0.x; v[1]=(__bf16)b0.y; v[2]=(__bf16)b0.z; v[3]=(__bf16)b0.w;
      v[4]=(__bf16)b1.x; v[5]=(__bf16)b1.y; v[6]=(__bf16)b1.z; v[7]=(__bf16)b1.w;
      *reinterpret_cast<bf16x8*>(&Bs[srow][scol]) = v;
      v[0]=(__bf16)b2.x; v[1]=(__bf16)b2.y; v[2]=(__bf16)b2.z; v[3]=(__bf16)b2.w;
      v[4]=(__bf16)b3.x; v[5]=(__bf16)b3.y; v[6]=(__bf16)b3.z; v[7]=(__bf16)b3.w;
      *reinterpret_cast<bf16x8*>(&Bs[srow][scol + 8]) = v;
    }
    __syncthreads();
    const int ko = (lane >> 4) << 3;
    bf16x8 af[4], bfr[4];
#pragma unroll
    for (int m16 = 0; m16 < 4; ++m16)
      af[m16] = *reinterpret_cast<const bf16x8*>(&As[wr * 64 + m16 * 16 + (lane & 15)][ko]);
#pragma unroll
    for (int n16 = 0; n16 < 4; ++n16)
      bfr[n16] = *reinterpret_cast<const bf16x8*>(&Bs[wc * 64 + n16 * 16 + (lane & 15)][ko]);
#pragma unroll
    for (int m16 = 0; m16 < 4; ++m16)
#pragma unroll
      for (int n16 = 0; n16 < 4; ++n16)
        acc[m16][n16] =
            __builtin_amdgcn_mfma_f32_16x16x32_bf16(af[m16], bfr[n16], acc[m16][n16], 0, 0, 0);
  }

#pragma unroll
  for (int n16 = 0; n16 < 4; ++n16) {
    const int col = n0 + wc * 64 + n16 * 16 + (lane & 15);
    const float bi = bias_n[col];
#pragma unroll
    for (int m16 = 0; m16 < 4; ++m16) {
#pragma unroll
      for (int q = 0; q < 4; ++q) {
        const size_t row = m0 + wr * 64 + m16 * 16 + ((lane >> 4) << 2) + q;
        pre[row * HDIM + col] = (__bf16)(acc[m16][n16][q] + bi);
      }
    }
  }
}

// ---------------------------------------------------------------------------
// Phase 2: persistent scan. grid=256, block=1024 (16 waves). WG -> (b, s):
// slice s owns h rows [64s, 64s+64). Wave w owns rows 4w..4w+3 end-to-end:
// matvec -> shfl-reduce (every lane holds its row's dot) -> lead lanes
// (lane&15==0) do pointwise + publish + y-store. Waves 1..15 then poll-gather
// one remote slice each. hvec double-buffered by parity; ONE barrier/step.
// ---------------------------------------------------------------------------
__global__ __launch_bounds__(1024) void leaky_scan(
    const __bf16* __restrict__ pre, const float* __restrict__ whh,
    const float* __restrict__ h0, const float* __restrict__ bias_z,
    const float* __restrict__ bias_r, float* __restrict__ y,
    float* __restrict__ hn, unsigned long long* hbuf) {
  __shared__ __align__(16) float hvec[2][HDIM];
  const int tid = threadIdx.x;
  const int lane = tid & 63;
  const int wid = tid >> 6;  // 0..15
  const int g = blockIdx.x;
  const int b = g & 15;   // batch
  const int s = g >> 4;   // slice
  const int base = s << 6;

  // my row (per 16-lane group): rloc = 4*wid + (lane>>4)
  const int rloc = (wid << 2) + (lane >> 4);
  const int R = base + rloc;
  const float* wrow = whh + (size_t)(2 * HDIM + R) * HDIM;
  const int cb = (lane & 15) << 2;
  f32x4 wreg[16];
#pragma unroll
  for (int c = 0; c < 16; ++c) {
    const int colc = cb + (c << 6);
    f32x4 v = *reinterpret_cast<const f32x4*>(wrow + colc);
    v[0] = (R == colc + 0) ? 0.f : v[0];
    v[1] = (R == colc + 1) ? 0.f : v[1];
    v[2] = (R == colc + 2) ? 0.f : v[2];
    v[3] = (R == colc + 3) ? 0.f : v[3];
    wreg[c] = v;
  }
  hvec[0][tid] = h0[b * HDIM + tid];
  const bool lead = (lane & 15) == 0;
  float zz = 0.f, rr = 0.f, preg = 0.f;
  if (lead) {
    zz = fast_sigmoid(bias_z[R]);
    rr = fast_sigmoid(bias_r[R]);
    preg = (float)pre[(size_t)b * HDIM + R];  // pre[t=0]
  }
  // remote-slice gather target for this wave (waves 1..15)
  const int sg = (s + wid) & 15;
  const int jg = (sg << 6) + lane;
  __syncthreads();

  for (int t = 1; t <= T_STEPS; ++t) {
    const int pc = t & 1;        // current parity (write h_t here)
    const float* hsrc = hvec[pc ^ 1];  // h_{t-1}

    // matvec: dot[R] = sum_j W[R][j] * h[j]  (4 split accumulators)
    float a0 = 0.f, a1 = 0.f, a2 = 0.f, a3 = 0.f;
#pragma unroll
    for (int c = 0; c < 4; ++c) {
      f32x4 h0v = *reinterpret_cast<const f32x4*>(&hsrc[cb + ((4 * c + 0) << 6)]);
      f32x4 h1v = *reinterpret_cast<const f32x4*>(&hsrc[cb + ((4 * c + 1) << 6)]);
      f32x4 h2v = *reinterpret_cast<const f32x4*>(&hsrc[cb + ((4 * c + 2) << 6)]);
      f32x4 h3v = *reinterpret_cast<const f32x4*>(&hsrc[cb + ((4 * c + 3) << 6)]);
      const f32x4 w0 = wreg[4 * c + 0], w1 = wreg[4 * c + 1];
      const f32x4 w2 = wreg[4 * c + 2], w3 = wreg[4 * c + 3];
      a0 += w0[0]*h0v[0] + w0[1]*h0v[1] + w0[2]*h0v[2] + w0[3]*h0v[3];
      a1 += w1[0]*h1v[0] + w1[1]*h1v[1] + w1[2]*h1v[2] + w1[3]*h1v[3];
      a2 += w2[0]*h2v[0] + w2[1]*h2v[1] + w2[2]*h2v[2] + w2[3]*h2v[3];
      a3 += w3[0]*h3v[0] + w3[1]*h3v[1] + w3[2]*h3v[2] + w3[3]*h3v[3];
    }
    float acc = (a0 + a1) + (a2 + a3);
    acc += __shfl_xor(acc, 1);
    acc += __shfl_xor(acc, 2);
    acc += __shfl_xor(acc, 4);
    acc += __shfl_xor(acc, 8);
    // every lane now holds its row's full dot

    const size_t slot = ((size_t)pc * NBATCH + b) << 10;  // parity buffer base

    if (lead) {
      // pointwise + publish for row R (4 lead lanes per wave)
      const float hp = hsrc[R];
      const float nn = fast_tanh(preg + rr * acc);
      const float hnew = zz * hp + (1.0f - zz) * nn;
      if (t < T_STEPS) {
        const unsigned long long pv =
            (unsigned long long)__float_as_uint(hnew) | ((unsigned long long)(unsigned)t << 32);
        (void)__hip_atomic_exchange(&hbuf[slot + R], pv, __ATOMIC_RELAXED,
                                    __HIP_MEMORY_SCOPE_AGENT);
      }
      hvec[pc][R] = hnew;  // own row locally
      y[((size_t)(t - 1) * NBATCH + b) * HDIM + R] = hnew;
      if (t < T_STEPS)
        preg = (float)pre[((size_t)t * NBATCH + b) * HDIM + R];  // prefetch t+1
      else
        hn[b * HDIM + R] = hnew;
    }
    if (wid > 0 && t < T_STEPS) {
      // poll my remote word until its embedded tag == t, then land it in LDS
      unsigned long long v;
      for (;;) {
        v = __hip_atomic_load(&hbuf[slot + jg], __ATOMIC_RELAXED, __HIP_MEMORY_SCOPE_AGENT);
        if ((unsigned)(v >> 32) == (unsigned)t) break;
        __builtin_amdgcn_s_sleep(1);  // throttle LLC poll traffic
      }
      hvec[pc][jg] = __uint_as_float((unsigned)v);
    }
    __syncthreads();  // hvec[pc] = h_t complete
  }
}

// ---------------------------------------------------------------------------
extern "C" void kernel_launch(void* const* d_in, const int* in_sizes, int n_in,
                              void* d_out, int out_size, void* d_ws, size_t ws_size,
                              hipStream_t stream) {
  const float* x = (const float*)d_in[0];
  const float* h0 = (const float*)d_in[1];
  const float* wih = (const float*)d_in[2];
  const float* whh = (const float*)d_in[3];
  const float* bz = (const float*)d_in[4];
  const float* bn = (const float*)d_in[5];
  const float* br = (const float*)d_in[6];
  float* y = (float*)d_out;
  float* hn = y + (size_t)T_STEPS * NBATCH * HDIM;

  // workspace: pre (bf16, 67MB) | hbuf (u64[2][16][1024], 256KB)
  __bf16* pre = (__bf16*)d_ws;
  unsigned long long* hbuf =
      (unsigned long long*)((char*)d_ws + (size_t)T_STEPS * NBATCH * HDIM * sizeof(__bf16));

  // no memset needed: tag-equality polling treats 0xAA poison as "not ready"
  pre_gemm<<<dim3(2048), dim3(256), 0, stream>>>(x, wih, bn, pre);
  leaky_scan<<<dim3(256), dim3(1024), 0, stream>>>(pre, whh, h0, bz, br, y, hn, hbuf);
}